// Round 4
// baseline (268.110 us; speedup 1.0000x reference)
//
#include <hip/hip_runtime.h>
#include <cstdint>
#include <cstddef>

#define BB 256
#define TB 2048
#define NROWS (BB*TB)          // 524288 rows of [64]
#define R1 128                 // rows per k1 block
#define NBLK1 (NROWS/R1)       // 4096

typedef float f32x4 __attribute__((ext_vector_type(4)));

// ---- workspace layout (bytes) ----
#define OFF_X      0ull
#define SZ_X       ((size_t)NROWS*64*4)            // 128 MiB raw x_proj [bt][h]
#define OFF_PART   (OFF_X + SZ_X)
#define SZ_PART    ((size_t)128*NBLK1*4)           // 2 MiB partials [ch][blk]
#define OFF_STAT   (OFF_PART + SZ_PART)
#define SZ_STAT    (128*8)                         // f64 col sums / sumsq
#define OFF_PARAM  (OFF_STAT + SZ_STAT)            // scale[64] shift[64] thresh[1024]
#define SZ_PARAM   ((size_t)(64+64+1024)*4)

// ============ K1: x_proj = kin @ W^T (raw) + per-block col sum/sumsq ============
// 128 rows x 64 cols per block; 128 threads; 8x8 thread tile; swizzled b128 LDS.
__global__ __launch_bounds__(128, 2) void k1_gemm(const float* __restrict__ kin,
                                                  const float* __restrict__ Wsp,
                                                  float* __restrict__ xproj,
                                                  float* __restrict__ partials) {
  __shared__ float4 As[R1 * 16];   // 32 KB, [r][cc ^ ((r>>2)&7)]
  __shared__ float4 Ws4[64 * 16];  // 16 KB, [h][cc ^ ((h>>2)&7)]
  const int tid = threadIdx.x;
  const size_t r0 = (size_t)blockIdx.x * R1;

  const f32x4* kin4 = (const f32x4*)(kin + r0 * 64);
  #pragma unroll
  for (int k = 0; k < 16; ++k) {
    int idx = k * 128 + tid;
    int r = idx >> 4, cc = idx & 15;
    f32x4 v = __builtin_nontemporal_load(&kin4[idx]);
    As[r * 16 + (cc ^ ((r >> 2) & 7))] = make_float4(v.x, v.y, v.z, v.w);
  }
  const float4* W4 = (const float4*)Wsp;
  #pragma unroll
  for (int k = 0; k < 8; ++k) {
    int idx = k * 128 + tid;
    int h = idx >> 4, cc = idx & 15;
    Ws4[h * 16 + (cc ^ ((h >> 2) & 7))] = W4[idx];
  }
  __syncthreads();

  const int ty = tid >> 3;   // 0..15 -> rows 8*ty..+7
  const int tx = tid & 7;    // cols 8*tx..+7
  float acc[8][8];
  #pragma unroll
  for (int i = 0; i < 8; ++i)
    #pragma unroll
    for (int j = 0; j < 8; ++j) acc[i][j] = 0.f;

  #pragma unroll 1
  for (int cc = 0; cc < 16; ++cc) {
    float4 av[8], wv[8];
    #pragma unroll
    for (int i = 0; i < 8; ++i)
      av[i] = As[(8 * ty + i) * 16 + (cc ^ ((2 * ty + (i >> 2)) & 7))];
    #pragma unroll
    for (int j = 0; j < 8; ++j)
      wv[j] = Ws4[(8 * tx + j) * 16 + (cc ^ ((2 * tx + (j >> 2)) & 7))];
    #pragma unroll
    for (int i = 0; i < 8; ++i)
      #pragma unroll
      for (int j = 0; j < 8; ++j) {
        // c ascending within chunk -> overall c = 0..63 sequential (matches ref)
        acc[i][j] = fmaf(av[i].x, wv[j].x, acc[i][j]);
        acc[i][j] = fmaf(av[i].y, wv[j].y, acc[i][j]);
        acc[i][j] = fmaf(av[i].z, wv[j].z, acc[i][j]);
        acc[i][j] = fmaf(av[i].w, wv[j].w, acc[i][j]);
      }
  }

  #pragma unroll
  for (int i = 0; i < 8; ++i) {
    const size_t row = r0 + 8 * ty + i;
    *(float4*)(xproj + row * 64 + 8 * tx) =
        make_float4(acc[i][0], acc[i][1], acc[i][2], acc[i][3]);
    *(float4*)(xproj + row * 64 + 8 * tx + 4) =
        make_float4(acc[i][4], acc[i][5], acc[i][6], acc[i][7]);
  }

  __syncthreads();                 // all waves done reading As/Ws4
  float* Sm = (float*)As;          // [64][17]
  float* Sq = Sm + 64 * 17;
  #pragma unroll
  for (int j = 0; j < 8; ++j) {
    const int col = 8 * tx + j;
    float s = 0.f, q = 0.f;
    #pragma unroll
    for (int i = 0; i < 8; ++i) {   // rows ascending within group
      s += acc[i][j];
      q += acc[i][j] * acc[i][j];
    }
    Sm[col * 17 + ty] = s;
    Sq[col * 17 + ty] = q;
  }
  __syncthreads();
  if (tid < 64) {
    float s = 0.f, q = 0.f;
    #pragma unroll
    for (int g = 0; g < 16; ++g) {  // row groups ascending -> rows 0..127 in order
      s += Sm[tid * 17 + g];
      q += Sq[tid * 17 + g];
    }
    partials[(size_t)tid * NBLK1 + blockIdx.x]        = s;
    partials[(size_t)(64 + tid) * NBLK1 + blockIdx.x] = q;
  }
}

// ============ K2a: deterministic f64 reduction (coalesced rows) ============
__global__ __launch_bounds__(256) void k2a_reduce(const float* __restrict__ partials,
                                                  double* __restrict__ statd) {
  __shared__ double sd[256];
  const int idx = blockIdx.x;              // 0..127
  double acc = 0.0;
  for (int k = threadIdx.x; k < NBLK1; k += 256)
    acc += (double)partials[(size_t)idx * NBLK1 + k];
  sd[threadIdx.x] = acc;
  __syncthreads();
  for (int s = 128; s > 0; s >>= 1) {
    if (threadIdx.x < s) sd[threadIdx.x] += sd[threadIdx.x + s];
    __syncthreads();
  }
  if (threadIdx.x == 0) statd[idx] = sd[0];
}

// ============ K2b: BN scale/shift + dynamic thresholds ============
__global__ __launch_bounds__(256) void k2b_final(const double* __restrict__ statd,
                                                 const float* __restrict__ gamma,
                                                 const float* __restrict__ beta,
                                                 const float* __restrict__ tda,
                                                 const float* __restrict__ Wtda,
                                                 const float* __restrict__ btda,
                                                 float* __restrict__ param) {
  const int tid = threadIdx.x;
  if (tid < 64) {
    double mean = statd[tid] / (double)NROWS;
    double ex2  = statd[64 + tid] / (double)NROWS;
    double var  = ex2 - mean * mean;
    double sc   = (double)gamma[tid] / sqrt(var + 1e-5);
    param[tid]      = (float)sc;
    param[64 + tid] = (float)((double)beta[tid] - mean * sc);
  }
  const int b = tid;
  #pragma unroll
  for (int j = 0; j < 4; ++j) {
    double acc = (double)btda[j];
    for (int k = 0; k < 50; ++k)
      acc += (double)tda[b * 50 + k] * (double)Wtda[j * 50 + k];
    double sig = 1.0 / (1.0 + exp(-acc));
    param[128 + b * 4 + j] = (float)(1.0 + 0.5 * sig);
  }
}

// ============ K3f: fused layer-1 scan + cur2 + layer-2 scan, wave per b ============
#define LOADX(BUF, TBASE)                             \
  { _Pragma("unroll") for (int i_ = 0; i_ < 64; ++i_) \
      BUF[i_] = xr[(size_t)((TBASE) + i_) * 64]; }

// layer-1 chunk: lane h = channel; lane i keeps ballot mask of t = TBASE+i;
// then each lane computes its t's cur2 (same fmaf order as old k4) -> LDS buf PB.
#define L1CUR2(CUR, NXT0, PB)                                        \
  { unsigned long long keep = 0ull;                                  \
    _Pragma("unroll") for (int i_ = 0; i_ < 64; ++i_) {              \
      bool sp = (mem >= 1.0f);                                       \
      unsigned long long mb = __ballot(sp);                          \
      if (h == i_) keep = mb;                                        \
      float xrn = (i_ < 63) ? CUR[(i_ + 1) & 63] : (NXT0);           \
      float xn = fmaf(xrn, sc, sh);                                  \
      mem = sp ? xn : fmaf(mem, 0.9f, xn);                           \
    }                                                                \
    float c0 = 0.f, c1 = 0.f, c2 = 0.f, c3 = 0.f;                    \
    _Pragma("unroll") for (int hh = 0; hh < 64; ++hh) {              \
      float4 w = WcT[hh];                                            \
      float bitf = (float)((unsigned)((keep >> hh) & 1ull));         \
      c0 = fmaf(bitf, w.x, c0); c1 = fmaf(bitf, w.y, c1);            \
      c2 = fmaf(bitf, w.z, c2); c3 = fmaf(bitf, w.w, c3);            \
    }                                                                \
    float o0, o1, o2, o3;                                            \
    { float cx = c0*latL[0];  cx = fmaf(c1, latL[4],  cx); cx = fmaf(c2, latL[8],  cx); cx = fmaf(c3, latL[12], cx); o0 = cx; } \
    { float cx = c0*latL[1];  cx = fmaf(c1, latL[5],  cx); cx = fmaf(c2, latL[9],  cx); cx = fmaf(c3, latL[13], cx); o1 = cx; } \
    { float cx = c0*latL[2];  cx = fmaf(c1, latL[6],  cx); cx = fmaf(c2, latL[10], cx); cx = fmaf(c3, latL[14], cx); o2 = cx; } \
    { float cx = c0*latL[3];  cx = fmaf(c1, latL[7],  cx); cx = fmaf(c2, latL[11], cx); cx = fmaf(c3, latL[15], cx); o3 = cx; } \
    lbuf[(PB) * 64 + h] = make_float4(o0, o1, o2, o3); }

// layer-2 chunk scan: all lanes run chain j = h&3 redundantly (no divergence);
// arithmetic identical to old k5 (sel : fmaf(mem,0.9,next)).
#define L2SCAN(PB, NB, HASNEXT)                                      \
  { float cv[64];                                                    \
    _Pragma("unroll") for (int i_ = 0; i_ < 64; ++i_)                \
      cv[i_] = lbufF[(PB) * 256 + i_ * 4 + jj];                      \
    float nv = (HASNEXT) ? lbufF[(NB) * 256 + jj] : 0.f;             \
    _Pragma("unroll") for (int i_ = 0; i_ < 64; ++i_) {              \
      bool sp2 = (mem2 >= th2);                                      \
      cnt += sp2 ? 1u : 0u;                                          \
      float xn2 = (i_ < 63) ? cv[(i_ + 1) & 63] : nv;                \
      mem2 = sp2 ? xn2 : fmaf(mem2, 0.9f, xn2);                      \
    } }

__global__ __launch_bounds__(64) void k3f(const float* __restrict__ xproj,
                                          const float* __restrict__ param,
                                          const float* __restrict__ Wc,
                                          const float* __restrict__ lat,
                                          float* __restrict__ out) {
  __shared__ float4 WcT[64];       // WcT[h] = (Wc[0][h],Wc[1][h],Wc[2][h],Wc[3][h])
  __shared__ float latL[16];
  __shared__ float4 lbuf[2 * 64];  // cur2 double buffer, [buf][t_in_chunk]
  float* lbufF = (float*)lbuf;

  const int b = blockIdx.x, h = threadIdx.x;
  const int jj = h & 3;
  WcT[h] = make_float4(Wc[h], Wc[64 + h], Wc[128 + h], Wc[192 + h]);
  if (h < 16) latL[h] = lat[h];
  __syncthreads();

  const float sc = param[h], sh = param[64 + h];
  const float th2 = param[128 + b * 4 + jj];
  const float* xr = xproj + (size_t)b * TB * 64 + h;

  float xa[64], xb[64];
  LOADX(xa, 0)
  LOADX(xb, 64)
  float mem = fmaf(xa[0], sc, sh);   // t=0 post-add state (0.9*0+x == x exactly)
  float mem2 = 0.f;
  unsigned cnt = 0;

  L1CUR2(xa, xb[0], 0)               // chunk 0 -> buf0
  LOADX(xa, 128)                     // chunk 2
  L1CUR2(xb, xa[0], 1)               // chunk 1 -> buf1
  mem2 = lbufF[jj];                  // layer-2 init: cur2[t=0][j]
  L2SCAN(0, 1, true)                 // scan chunk 0
  LOADX(xb, 192)                     // chunk 3

  #pragma unroll 1
  for (int cc = 1; cc <= 14; ++cc) {
    const int t0 = cc * 128;
    L1CUR2(xa, xb[0], 0)             // chunk 2cc -> buf0
    LOADX(xa, t0 + 128)              // chunk 2cc+2
    L2SCAN(1, 0, true)               // scan chunk 2cc-1
    L1CUR2(xb, xa[0], 1)             // chunk 2cc+1 -> buf1
    LOADX(xb, t0 + 192)              // chunk 2cc+3
    L2SCAN(0, 1, true)               // scan chunk 2cc
  }
  // epilogue: chunks 30 (xa), 31 (xb)
  L1CUR2(xa, xb[0], 0)               // chunk 30 -> buf0
  L2SCAN(1, 0, true)                 // scan chunk 29
  L1CUR2(xb, 0.f, 1)                 // chunk 31 -> buf1 (trailing x dead)
  L2SCAN(0, 1, true)                 // scan chunk 30
  L2SCAN(1, 0, false)                // scan chunk 31 (trailing cur2 dead)

  if (h < 4) out[b * 4 + h] = (float)cnt;
}

extern "C" void kernel_launch(void* const* d_in, const int* in_sizes, int n_in,
                              void* d_out, int out_size, void* d_ws, size_t ws_size,
                              hipStream_t stream) {
  const float* kin   = (const float*)d_in[0];
  const float* tda   = (const float*)d_in[1];
  const float* Wsp   = (const float*)d_in[2];
  const float* gamma = (const float*)d_in[3];
  const float* beta  = (const float*)d_in[4];
  const float* Wc    = (const float*)d_in[5];
  const float* lat   = (const float*)d_in[6];
  const float* Wtda  = (const float*)d_in[7];
  const float* btda  = (const float*)d_in[8];

  char* ws = (char*)d_ws;
  float*  xproj    = (float*)(ws + OFF_X);
  float*  partials = (float*)(ws + OFF_PART);
  double* statd    = (double*)(ws + OFF_STAT);
  float*  param    = (float*)(ws + OFF_PARAM);
  float*  out      = (float*)d_out;

  k1_gemm  <<<dim3(NBLK1), dim3(128), 0, stream>>>(kin, Wsp, xproj, partials);
  k2a_reduce<<<dim3(128),  dim3(256), 0, stream>>>(partials, statd);
  k2b_final<<<dim3(1),     dim3(256), 0, stream>>>(statd, gamma, beta, tda, Wtda, btda, param);
  k3f      <<<dim3(BB),    dim3(64),  0, stream>>>(xproj, param, Wc, lat, out);
}

// Round 5
// 178.432 us; speedup vs baseline: 1.5026x; 1.5026x over previous
//
#include <hip/hip_runtime.h>
#include <cstdint>
#include <cstddef>

#define BB 256
#define TB 2048
#define NROWS (BB*TB)          // 524288 rows of [64]
#define R1 128                 // rows per k1 block
#define NBLK1 (NROWS/R1)       // 4096

typedef float f32x4 __attribute__((ext_vector_type(4)));

// ---- workspace layout (bytes) ----
#define OFF_X      0ull
#define SZ_X       ((size_t)NROWS*64*4)            // 128 MiB raw x_proj [bt][h]
#define OFF_PART   (OFF_X + SZ_X)
#define SZ_PART    ((size_t)128*NBLK1*4)           // 2 MiB partials [ch][blk]
#define OFF_STAT   (OFF_PART + SZ_PART)
#define SZ_STAT    (128*8)                         // f64 col sums / sumsq
#define OFF_PARAM  (OFF_STAT + SZ_STAT)            // scale[64] shift[64] thresh[1024]
#define SZ_PARAM   ((size_t)(64+64+1024)*4)
#define OFF_MASK   ((OFF_PARAM + SZ_PARAM + 255ull) & ~255ull)
#define SZ_MASK    ((size_t)NROWS*8)               // 4 MiB spike masks [b][t]
#define OFF_CUR2   (OFF_MASK + SZ_MASK)
#define SZ_CUR2    ((size_t)NROWS*4*4)             // 8 MiB cur2T [b*4+j][t]

// ============ K1: x_proj = kin @ W^T (raw) + per-block col sum/sumsq ============
// 128 rows x 64 cols per block; 128 threads; 8x8 thread tile; swizzled b128 LDS.
__global__ __launch_bounds__(128, 2) void k1_gemm(const float* __restrict__ kin,
                                                  const float* __restrict__ Wsp,
                                                  float* __restrict__ xproj,
                                                  float* __restrict__ partials) {
  __shared__ float4 As[R1 * 16];   // 32 KB, [r][cc ^ ((r>>2)&7)]
  __shared__ float4 Ws4[64 * 16];  // 16 KB, [h][cc ^ ((h>>2)&7)]
  const int tid = threadIdx.x;
  const size_t r0 = (size_t)blockIdx.x * R1;

  const f32x4* kin4 = (const f32x4*)(kin + r0 * 64);
  #pragma unroll
  for (int k = 0; k < 16; ++k) {
    int idx = k * 128 + tid;
    int r = idx >> 4, cc = idx & 15;
    f32x4 v = __builtin_nontemporal_load(&kin4[idx]);
    As[r * 16 + (cc ^ ((r >> 2) & 7))] = make_float4(v.x, v.y, v.z, v.w);
  }
  const float4* W4 = (const float4*)Wsp;
  #pragma unroll
  for (int k = 0; k < 8; ++k) {
    int idx = k * 128 + tid;
    int h = idx >> 4, cc = idx & 15;
    Ws4[h * 16 + (cc ^ ((h >> 2) & 7))] = W4[idx];
  }
  __syncthreads();

  const int ty = tid >> 3;   // 0..15 -> rows 8*ty..+7
  const int tx = tid & 7;    // cols 8*tx..+7
  float acc[8][8];
  #pragma unroll
  for (int i = 0; i < 8; ++i)
    #pragma unroll
    for (int j = 0; j < 8; ++j) acc[i][j] = 0.f;

  #pragma unroll 1
  for (int cc = 0; cc < 16; ++cc) {
    float4 av[8], wv[8];
    #pragma unroll
    for (int i = 0; i < 8; ++i)
      av[i] = As[(8 * ty + i) * 16 + (cc ^ ((2 * ty + (i >> 2)) & 7))];
    #pragma unroll
    for (int j = 0; j < 8; ++j)
      wv[j] = Ws4[(8 * tx + j) * 16 + (cc ^ ((2 * tx + (j >> 2)) & 7))];
    #pragma unroll
    for (int i = 0; i < 8; ++i)
      #pragma unroll
      for (int j = 0; j < 8; ++j) {
        acc[i][j] = fmaf(av[i].x, wv[j].x, acc[i][j]);
        acc[i][j] = fmaf(av[i].y, wv[j].y, acc[i][j]);
        acc[i][j] = fmaf(av[i].z, wv[j].z, acc[i][j]);
        acc[i][j] = fmaf(av[i].w, wv[j].w, acc[i][j]);
      }
  }

  #pragma unroll
  for (int i = 0; i < 8; ++i) {
    const size_t row = r0 + 8 * ty + i;
    *(float4*)(xproj + row * 64 + 8 * tx) =
        make_float4(acc[i][0], acc[i][1], acc[i][2], acc[i][3]);
    *(float4*)(xproj + row * 64 + 8 * tx + 4) =
        make_float4(acc[i][4], acc[i][5], acc[i][6], acc[i][7]);
  }

  __syncthreads();                 // all waves done reading As/Ws4
  float* Sm = (float*)As;          // [64][17]
  float* Sq = Sm + 64 * 17;
  #pragma unroll
  for (int j = 0; j < 8; ++j) {
    const int col = 8 * tx + j;
    float s = 0.f, q = 0.f;
    #pragma unroll
    for (int i = 0; i < 8; ++i) {
      s += acc[i][j];
      q += acc[i][j] * acc[i][j];
    }
    Sm[col * 17 + ty] = s;
    Sq[col * 17 + ty] = q;
  }
  __syncthreads();
  if (tid < 64) {
    float s = 0.f, q = 0.f;
    #pragma unroll
    for (int g = 0; g < 16; ++g) {
      s += Sm[tid * 17 + g];
      q += Sq[tid * 17 + g];
    }
    partials[(size_t)tid * NBLK1 + blockIdx.x]        = s;
    partials[(size_t)(64 + tid) * NBLK1 + blockIdx.x] = q;
  }
}

// ============ K2a: deterministic f64 reduction (coalesced rows) ============
__global__ __launch_bounds__(256) void k2a_reduce(const float* __restrict__ partials,
                                                  double* __restrict__ statd) {
  __shared__ double sd[256];
  const int idx = blockIdx.x;              // 0..127
  double acc = 0.0;
  for (int k = threadIdx.x; k < NBLK1; k += 256)
    acc += (double)partials[(size_t)idx * NBLK1 + k];
  sd[threadIdx.x] = acc;
  __syncthreads();
  for (int s = 128; s > 0; s >>= 1) {
    if (threadIdx.x < s) sd[threadIdx.x] += sd[threadIdx.x + s];
    __syncthreads();
  }
  if (threadIdx.x == 0) statd[idx] = sd[0];
}

// ============ K2b: BN scale/shift + dynamic thresholds ============
__global__ __launch_bounds__(256) void k2b_final(const double* __restrict__ statd,
                                                 const float* __restrict__ gamma,
                                                 const float* __restrict__ beta,
                                                 const float* __restrict__ tda,
                                                 const float* __restrict__ Wtda,
                                                 const float* __restrict__ btda,
                                                 float* __restrict__ param) {
  const int tid = threadIdx.x;
  if (tid < 64) {
    double mean = statd[tid] / (double)NROWS;
    double ex2  = statd[64 + tid] / (double)NROWS;
    double var  = ex2 - mean * mean;
    double sc   = (double)gamma[tid] / sqrt(var + 1e-5);
    param[tid]      = (float)sc;
    param[64 + tid] = (float)((double)beta[tid] - mean * sc);
  }
  const int b = tid;
  #pragma unroll
  for (int j = 0; j < 4; ++j) {
    double acc = (double)btda[j];
    for (int k = 0; k < 50; ++k)
      acc += (double)tda[b * 50 + k] * (double)Wtda[j * 50 + k];
    double sig = 1.0 / (1.0 + exp(-acc));
    param[128 + b * 4 + j] = (float)(1.0 + 0.5 * sig);
  }
}

// ============ K3: layer-1 LIF scan, wave per b, lane = channel h ============
#define K3_LOAD(BUF, TBASE)                         \
  { _Pragma("unroll") for (int i_ = 0; i_ < 64; ++i_) \
      BUF[i_] = xr[(size_t)((TBASE) + i_) * 64]; }

#define K3_CHUNK(CUR, NXT0, TBASE)                                   \
  { unsigned long long keep = 0;                                     \
    _Pragma("unroll") for (int i_ = 0; i_ < 64; ++i_) {              \
      bool sp = (mem >= 1.0f);                                       \
      unsigned long long mb = __ballot(sp);                          \
      if (h == i_) keep = mb;                                        \
      float xrn = (i_ < 63) ? CUR[(i_ + 1) & 63] : (NXT0);           \
      float xn = fmaf(xrn, sc, sh);                                  \
      mem = sp ? xn : fmaf(mem, 0.9f, xn);                           \
    }                                                                \
    masksB[(size_t)b * TB + (TBASE) + h] = keep; }

__global__ __launch_bounds__(64) void k3_scan1(const float* __restrict__ xproj,
                                               const float* __restrict__ param,
                                               unsigned long long* __restrict__ masksB) {
  const int b = blockIdx.x, h = threadIdx.x;
  const float sc = param[h], sh = param[64 + h];
  const float* xr = xproj + (size_t)b * TB * 64 + h;
  float xa[64], xb[64];

  K3_LOAD(xa, 0)
  float mem = fmaf(xa[0], sc, sh);   // t=0 post-add state

  #pragma unroll 1
  for (int t0 = 0; t0 < TB; t0 += 128) {
    K3_LOAD(xb, t0 + 64)
    K3_CHUNK(xa, xb[0], t0)
    if (t0 + 128 < TB) { K3_LOAD(xa, t0 + 128) }
    K3_CHUNK(xb, xa[0], t0 + 64)    // final chunk: trailing xa[0] is dead
  }
}

// ============ K4: cur2T[(b*4+j)][t] from bitmasks (grid over b) ============
__global__ __launch_bounds__(256) void k4_cur2(const unsigned long long* __restrict__ masksB,
                                               const float* __restrict__ Wc,
                                               const float* __restrict__ lat,
                                               float* __restrict__ cur2T) {
  __shared__ float WcL[256];
  __shared__ float latL[16];
  const int tid = threadIdx.x, b = blockIdx.x;
  WcL[tid] = Wc[tid];
  if (tid < 16) latL[tid] = lat[tid];
  __syncthreads();

  #pragma unroll 1
  for (int c = 0; c < 8; ++c) {
    const int t = c * 256 + tid;
    const unsigned long long m = masksB[(size_t)b * TB + t];
    const unsigned lo = (unsigned)m, hi = (unsigned)(m >> 32);
    float v0 = 0.f, v1 = 0.f, v2 = 0.f, v3 = 0.f;
    #pragma unroll
    for (int hh = 0; hh < 32; ++hh) {
      const float bit = (float)((lo >> hh) & 1u);
      v0 = fmaf(bit, WcL[hh],       v0);
      v1 = fmaf(bit, WcL[64 + hh],  v1);
      v2 = fmaf(bit, WcL[128 + hh], v2);
      v3 = fmaf(bit, WcL[192 + hh], v3);
    }
    #pragma unroll
    for (int hh = 32; hh < 64; ++hh) {
      const float bit = (float)((hi >> (hh - 32)) & 1u);
      v0 = fmaf(bit, WcL[hh],       v0);
      v1 = fmaf(bit, WcL[64 + hh],  v1);
      v2 = fmaf(bit, WcL[128 + hh], v2);
      v3 = fmaf(bit, WcL[192 + hh], v3);
    }
    float o0, o1, o2, o3;
    { float cx = v0 * latL[0];  cx = fmaf(v1, latL[4],  cx); cx = fmaf(v2, latL[8],  cx); cx = fmaf(v3, latL[12], cx); o0 = cx; }
    { float cx = v0 * latL[1];  cx = fmaf(v1, latL[5],  cx); cx = fmaf(v2, latL[9],  cx); cx = fmaf(v3, latL[13], cx); o1 = cx; }
    { float cx = v0 * latL[2];  cx = fmaf(v1, latL[6],  cx); cx = fmaf(v2, latL[10], cx); cx = fmaf(v3, latL[14], cx); o2 = cx; }
    { float cx = v0 * latL[3];  cx = fmaf(v1, latL[7],  cx); cx = fmaf(v2, latL[11], cx); cx = fmaf(v3, latL[15], cx); o3 = cx; }
    cur2T[(size_t)(b * 4 + 0) * TB + t] = o0;
    cur2T[(size_t)(b * 4 + 1) * TB + t] = o1;
    cur2T[(size_t)(b * 4 + 2) * TB + t] = o2;
    cur2T[(size_t)(b * 4 + 3) * TB + t] = o3;
  }
}

// ============ K5: layer-2 LIF scan, thread per (b, class), contiguous reads ============
#define K5_LOAD(BUF, TBASE)                                              \
  { _Pragma("unroll") for (int k_ = 0; k_ < 16; ++k_) {                  \
      float4 v = cr[((TBASE) >> 2) + k_];                                \
      BUF[4 * k_] = v.x; BUF[4 * k_ + 1] = v.y;                          \
      BUF[4 * k_ + 2] = v.z; BUF[4 * k_ + 3] = v.w; } }

#define K5_CHUNK(CUR, NXT0)                                   \
  { _Pragma("unroll") for (int i_ = 0; i_ < 64; ++i_) {       \
      bool sp = (mem >= th);                                  \
      cnt += sp ? 1u : 0u;                                    \
      float xn = (i_ < 63) ? CUR[(i_ + 1) & 63] : (NXT0);     \
      mem = sp ? xn : fmaf(mem, 0.9f, xn);                    \
    } }

__global__ __launch_bounds__(64) void k5_scan2(const float* __restrict__ cur2T,
                                               const float* __restrict__ param,
                                               float* __restrict__ out) {
  const int g = blockIdx.x * 64 + threadIdx.x;   // 0..1023 = b*4 + j
  const float th = param[128 + g];
  const float4* cr = (const float4*)(cur2T + (size_t)g * TB);
  float ca[64], cb[64];

  K5_LOAD(ca, 0)
  float mem = ca[0];
  unsigned cnt = 0;

  #pragma unroll 1
  for (int t0 = 0; t0 < TB; t0 += 128) {
    K5_LOAD(cb, t0 + 64)
    K5_CHUNK(ca, cb[0])
    if (t0 + 128 < TB) { K5_LOAD(ca, t0 + 128) }
    K5_CHUNK(cb, ca[0])
  }
  out[g] = (float)cnt;
}

extern "C" void kernel_launch(void* const* d_in, const int* in_sizes, int n_in,
                              void* d_out, int out_size, void* d_ws, size_t ws_size,
                              hipStream_t stream) {
  const float* kin   = (const float*)d_in[0];
  const float* tda   = (const float*)d_in[1];
  const float* Wsp   = (const float*)d_in[2];
  const float* gamma = (const float*)d_in[3];
  const float* beta  = (const float*)d_in[4];
  const float* Wc    = (const float*)d_in[5];
  const float* lat   = (const float*)d_in[6];
  const float* Wtda  = (const float*)d_in[7];
  const float* btda  = (const float*)d_in[8];

  char* ws = (char*)d_ws;
  float*  xproj    = (float*)(ws + OFF_X);
  float*  partials = (float*)(ws + OFF_PART);
  double* statd    = (double*)(ws + OFF_STAT);
  float*  param    = (float*)(ws + OFF_PARAM);
  unsigned long long* masksB = (unsigned long long*)(ws + OFF_MASK);
  float*  cur2T    = (float*)(ws + OFF_CUR2);
  float*  out      = (float*)d_out;

  k1_gemm  <<<dim3(NBLK1), dim3(128), 0, stream>>>(kin, Wsp, xproj, partials);
  k2a_reduce<<<dim3(128),  dim3(256), 0, stream>>>(partials, statd);
  k2b_final<<<dim3(1),     dim3(256), 0, stream>>>(statd, gamma, beta, tda, Wtda, btda, param);
  k3_scan1 <<<dim3(BB),    dim3(64),  0, stream>>>(xproj, param, masksB);
  k4_cur2  <<<dim3(BB),    dim3(256), 0, stream>>>(masksB, Wc, lat, cur2T);
  k5_scan2 <<<dim3(16),    dim3(64),  0, stream>>>(cur2T, param, out);
}

// Round 6
// 163.691 us; speedup vs baseline: 1.6379x; 1.0901x over previous
//
#include <hip/hip_runtime.h>
#include <cstdint>
#include <cstddef>

#define BB 256
#define TB 2048
#define NROWS (BB*TB)          // 524288 rows of [64]
#define R1 256                 // rows per k1 block
#define NBLK_K1 (NROWS/R1)     // 2048 blocks
#define NBLK1 4096             // partial-sum granularity: 128-row groups (bit-compat w/ R5)

typedef float f32x4 __attribute__((ext_vector_type(4)));

// ---- workspace layout (bytes) ----
#define OFF_X      0ull
#define SZ_X       ((size_t)NROWS*64*4)            // 128 MiB raw x_proj [bt][h]
#define OFF_PART   (OFF_X + SZ_X)
#define SZ_PART    ((size_t)128*NBLK1*4)           // 2 MiB partials [ch][4096]
#define OFF_STAT   (OFF_PART + SZ_PART)
#define SZ_STAT    (128*8)                         // f64 col sums / sumsq
#define OFF_PARAM  (OFF_STAT + SZ_STAT)            // scale[64] shift[64] thresh[1024]
#define SZ_PARAM   ((size_t)(64+64+1024)*4)
#define OFF_MASK   ((OFF_PARAM + SZ_PARAM + 255ull) & ~255ull)
#define SZ_MASK    ((size_t)NROWS*8)               // 4 MiB spike masks [b][t]
#define OFF_CUR2   (OFF_MASK + SZ_MASK)
#define SZ_CUR2    ((size_t)NROWS*4*4)             // 8 MiB cur2T [b*4+j][t]

// ============ K1: x_proj = kin @ W^T (raw) + 128-row-granular col sum/sumsq ============
// 256 rows x 64 cols per block; 256 threads; 8x8 thread tile; XOR-(r>>3) swizzled b128 LDS.
// LDS: As 64 KB + Ws 16 KB = 80 KB -> 2 blocks/CU (160 KB), 8 waves/CU.
__global__ __launch_bounds__(256, 2) void k1_gemm(const float* __restrict__ kin,
                                                  const float* __restrict__ Wsp,
                                                  float* __restrict__ xproj,
                                                  float* __restrict__ partials) {
  __shared__ float4 As[R1 * 16];   // 64 KB, [r][cc ^ ((r>>3)&7)]
  __shared__ float4 Ws4[64 * 16];  // 16 KB, [h][cc ^ ((h>>3)&7)]
  const int tid = threadIdx.x;
  const size_t r0 = (size_t)blockIdx.x * R1;

  // stage A: 4096 float4, 16 per thread, coalesced, nontemporal (streamed once)
  const f32x4* kin4 = (const f32x4*)(kin + r0 * 64);
  #pragma unroll
  for (int k = 0; k < 16; ++k) {
    int idx = k * 256 + tid;
    int r = idx >> 4, cc = idx & 15;
    f32x4 v = __builtin_nontemporal_load(&kin4[idx]);
    As[r * 16 + (cc ^ ((r >> 3) & 7))] = make_float4(v.x, v.y, v.z, v.w);
  }
  const float4* W4 = (const float4*)Wsp;
  #pragma unroll
  for (int k = 0; k < 4; ++k) {
    int idx = k * 256 + tid;
    int h = idx >> 4, cc = idx & 15;
    Ws4[h * 16 + (cc ^ ((h >> 3) & 7))] = W4[idx];
  }
  __syncthreads();

  const int ty = tid >> 3;   // 0..31 -> rows 8*ty..+7
  const int tx = tid & 7;    // cols 8*tx..+7
  float acc[8][8];
  #pragma unroll
  for (int i = 0; i < 8; ++i)
    #pragma unroll
    for (int j = 0; j < 8; ++j) acc[i][j] = 0.f;

  #pragma unroll 1
  for (int cc = 0; cc < 16; ++cc) {
    float4 av[8], wv[8];
    #pragma unroll
    for (int i = 0; i < 8; ++i)
      av[i] = As[(8 * ty + i) * 16 + (cc ^ (ty & 7))];       // (8ty+i)>>3 == ty
    #pragma unroll
    for (int j = 0; j < 8; ++j)
      wv[j] = Ws4[(8 * tx + j) * 16 + (cc ^ tx)];            // (8tx+j)>>3 == tx
    #pragma unroll
    for (int i = 0; i < 8; ++i)
      #pragma unroll
      for (int j = 0; j < 8; ++j) {
        // c ascending: 4cc+0..3 -> overall c = 0..63 sequential (matches ref order)
        acc[i][j] = fmaf(av[i].x, wv[j].x, acc[i][j]);
        acc[i][j] = fmaf(av[i].y, wv[j].y, acc[i][j]);
        acc[i][j] = fmaf(av[i].z, wv[j].z, acc[i][j]);
        acc[i][j] = fmaf(av[i].w, wv[j].w, acc[i][j]);
      }
  }

  #pragma unroll
  for (int i = 0; i < 8; ++i) {
    const size_t row = r0 + 8 * ty + i;
    *(float4*)(xproj + row * 64 + 8 * tx) =
        make_float4(acc[i][0], acc[i][1], acc[i][2], acc[i][3]);
    *(float4*)(xproj + row * 64 + 8 * tx + 4) =
        make_float4(acc[i][4], acc[i][5], acc[i][6], acc[i][7]);
  }

  __syncthreads();                 // all waves done reading As/Ws4
  float* Sm = (float*)As;          // [64][33] row-group sums
  float* Sq = Sm + 64 * 33;
  #pragma unroll
  for (int j = 0; j < 8; ++j) {
    const int col = 8 * tx + j;
    float s = 0.f, q = 0.f;
    #pragma unroll
    for (int i = 0; i < 8; ++i) {  // rows ascending within group
      s += acc[i][j];
      q += acc[i][j] * acc[i][j];
    }
    Sm[col * 33 + ty] = s;
    Sq[col * 33 + ty] = q;
  }
  __syncthreads();
  if (tid < 64) {
    // two 128-row partials, bit-identical values/order to the 128-row k1 (R5)
    float s0 = 0.f, q0 = 0.f, s1 = 0.f, q1 = 0.f;
    #pragma unroll
    for (int g = 0; g < 16; ++g)  { s0 += Sm[tid * 33 + g]; q0 += Sq[tid * 33 + g]; }
    #pragma unroll
    for (int g = 16; g < 32; ++g) { s1 += Sm[tid * 33 + g]; q1 += Sq[tid * 33 + g]; }
    const size_t p0 = 2 * (size_t)blockIdx.x;
    partials[(size_t)tid * NBLK1 + p0]            = s0;
    partials[(size_t)tid * NBLK1 + p0 + 1]        = s1;
    partials[(size_t)(64 + tid) * NBLK1 + p0]     = q0;
    partials[(size_t)(64 + tid) * NBLK1 + p0 + 1] = q1;
  }
}

// ============ K2a: deterministic f64 reduction (coalesced rows) ============
__global__ __launch_bounds__(256) void k2a_reduce(const float* __restrict__ partials,
                                                  double* __restrict__ statd) {
  __shared__ double sd[256];
  const int idx = blockIdx.x;              // 0..127
  double acc = 0.0;
  for (int k = threadIdx.x; k < NBLK1; k += 256)
    acc += (double)partials[(size_t)idx * NBLK1 + k];
  sd[threadIdx.x] = acc;
  __syncthreads();
  for (int s = 128; s > 0; s >>= 1) {
    if (threadIdx.x < s) sd[threadIdx.x] += sd[threadIdx.x + s];
    __syncthreads();
  }
  if (threadIdx.x == 0) statd[idx] = sd[0];
}

// ============ K2b: BN scale/shift + dynamic thresholds (parallel, 5 blocks) ============
__global__ __launch_bounds__(256) void k2b_final(const double* __restrict__ statd,
                                                 const float* __restrict__ gamma,
                                                 const float* __restrict__ beta,
                                                 const float* __restrict__ tda,
                                                 const float* __restrict__ Wtda,
                                                 const float* __restrict__ btda,
                                                 float* __restrict__ param) {
  const int tid = threadIdx.x, blk = blockIdx.x;
  if (blk == 4) {
    if (tid < 64) {
      double mean = statd[tid] / (double)NROWS;
      double ex2  = statd[64 + tid] / (double)NROWS;
      double var  = ex2 - mean * mean;
      double sc   = (double)gamma[tid] / sqrt(var + 1e-5);
      param[tid]      = (float)sc;
      param[64 + tid] = (float)((double)beta[tid] - mean * sc);
    }
    return;
  }
  const int g = blk * 256 + tid;           // 0..1023 = b*4 + j
  const int b = g >> 2, j = g & 3;
  double acc = (double)btda[j];
  for (int k = 0; k < 50; ++k)
    acc += (double)tda[b * 50 + k] * (double)Wtda[j * 50 + k];
  double sig = 1.0 / (1.0 + exp(-acc));
  param[128 + g] = (float)(1.0 + 0.5 * sig);
}

// ============ K3: layer-1 LIF scan, wave per b, lane = channel h ============
#define K3_LOAD(BUF, TBASE)                         \
  { _Pragma("unroll") for (int i_ = 0; i_ < 64; ++i_) \
      BUF[i_] = xr[(size_t)((TBASE) + i_) * 64]; }

#define K3_CHUNK(CUR, NXT0, TBASE)                                   \
  { unsigned long long keep = 0;                                     \
    _Pragma("unroll") for (int i_ = 0; i_ < 64; ++i_) {              \
      bool sp = (mem >= 1.0f);                                       \
      unsigned long long mb = __ballot(sp);                          \
      if (h == i_) keep = mb;                                        \
      float xrn = (i_ < 63) ? CUR[(i_ + 1) & 63] : (NXT0);           \
      float xn = fmaf(xrn, sc, sh);                                  \
      mem = sp ? xn : fmaf(mem, 0.9f, xn);                           \
    }                                                                \
    masksB[(size_t)b * TB + (TBASE) + h] = keep; }

__global__ __launch_bounds__(64) void k3_scan1(const float* __restrict__ xproj,
                                               const float* __restrict__ param,
                                               unsigned long long* __restrict__ masksB) {
  const int b = blockIdx.x, h = threadIdx.x;
  const float sc = param[h], sh = param[64 + h];
  const float* xr = xproj + (size_t)b * TB * 64 + h;
  float xa[64], xb[64];

  K3_LOAD(xa, 0)
  float mem = fmaf(xa[0], sc, sh);   // t=0 post-add state

  #pragma unroll 1
  for (int t0 = 0; t0 < TB; t0 += 128) {
    K3_LOAD(xb, t0 + 64)
    K3_CHUNK(xa, xb[0], t0)
    if (t0 + 128 < TB) { K3_LOAD(xa, t0 + 128) }
    K3_CHUNK(xb, xa[0], t0 + 64)    // final chunk: trailing xa[0] is dead
  }
}

// ============ K4: cur2T[(b*4+j)][t] from bitmasks (grid over b) ============
__global__ __launch_bounds__(256) void k4_cur2(const unsigned long long* __restrict__ masksB,
                                               const float* __restrict__ Wc,
                                               const float* __restrict__ lat,
                                               float* __restrict__ cur2T) {
  __shared__ float WcL[256];
  __shared__ float latL[16];
  const int tid = threadIdx.x, b = blockIdx.x;
  WcL[tid] = Wc[tid];
  if (tid < 16) latL[tid] = lat[tid];
  __syncthreads();

  #pragma unroll 1
  for (int c = 0; c < 8; ++c) {
    const int t = c * 256 + tid;
    const unsigned long long m = masksB[(size_t)b * TB + t];
    const unsigned lo = (unsigned)m, hi = (unsigned)(m >> 32);
    float v0 = 0.f, v1 = 0.f, v2 = 0.f, v3 = 0.f;
    #pragma unroll
    for (int hh = 0; hh < 32; ++hh) {
      const float bit = (float)((lo >> hh) & 1u);
      v0 = fmaf(bit, WcL[hh],       v0);
      v1 = fmaf(bit, WcL[64 + hh],  v1);
      v2 = fmaf(bit, WcL[128 + hh], v2);
      v3 = fmaf(bit, WcL[192 + hh], v3);
    }
    #pragma unroll
    for (int hh = 32; hh < 64; ++hh) {
      const float bit = (float)((hi >> (hh - 32)) & 1u);
      v0 = fmaf(bit, WcL[hh],       v0);
      v1 = fmaf(bit, WcL[64 + hh],  v1);
      v2 = fmaf(bit, WcL[128 + hh], v2);
      v3 = fmaf(bit, WcL[192 + hh], v3);
    }
    float o0, o1, o2, o3;
    { float cx = v0 * latL[0];  cx = fmaf(v1, latL[4],  cx); cx = fmaf(v2, latL[8],  cx); cx = fmaf(v3, latL[12], cx); o0 = cx; }
    { float cx = v0 * latL[1];  cx = fmaf(v1, latL[5],  cx); cx = fmaf(v2, latL[9],  cx); cx = fmaf(v3, latL[13], cx); o1 = cx; }
    { float cx = v0 * latL[2];  cx = fmaf(v1, latL[6],  cx); cx = fmaf(v2, latL[10], cx); cx = fmaf(v3, latL[14], cx); o2 = cx; }
    { float cx = v0 * latL[3];  cx = fmaf(v1, latL[7],  cx); cx = fmaf(v2, latL[11], cx); cx = fmaf(v3, latL[15], cx); o3 = cx; }
    cur2T[(size_t)(b * 4 + 0) * TB + t] = o0;
    cur2T[(size_t)(b * 4 + 1) * TB + t] = o1;
    cur2T[(size_t)(b * 4 + 2) * TB + t] = o2;
    cur2T[(size_t)(b * 4 + 3) * TB + t] = o3;
  }
}

// ============ K5: layer-2 LIF scan, block per b, lanes mirror 4 chains ============
#define K5_LOAD(BUF, TBASE)                                              \
  { _Pragma("unroll") for (int k_ = 0; k_ < 16; ++k_) {                  \
      float4 v = cr[((TBASE) >> 2) + k_];                                \
      BUF[4 * k_] = v.x; BUF[4 * k_ + 1] = v.y;                          \
      BUF[4 * k_ + 2] = v.z; BUF[4 * k_ + 3] = v.w; } }

#define K5_CHUNK(CUR, NXT0)                                   \
  { _Pragma("unroll") for (int i_ = 0; i_ < 64; ++i_) {       \
      bool sp = (mem >= th);                                  \
      cnt += sp ? 1u : 0u;                                    \
      float xn = (i_ < 63) ? CUR[(i_ + 1) & 63] : (NXT0);     \
      mem = sp ? xn : fmaf(mem, 0.9f, xn);                    \
    } }

__global__ __launch_bounds__(64) void k5_scan2(const float* __restrict__ cur2T,
                                               const float* __restrict__ param,
                                               float* __restrict__ out) {
  const int b = blockIdx.x;                      // 0..255
  const int j4 = threadIdx.x & 3;                // 16-way redundant lanes, identical math
  const int g = b * 4 + j4;
  const float th = param[128 + g];
  const float4* cr = (const float4*)(cur2T + (size_t)g * TB);
  float ca[64], cb[64];

  K5_LOAD(ca, 0)
  float mem = ca[0];
  unsigned cnt = 0;

  #pragma unroll 1
  for (int t0 = 0; t0 < TB; t0 += 128) {
    K5_LOAD(cb, t0 + 64)
    K5_CHUNK(ca, cb[0])
    if (t0 + 128 < TB) { K5_LOAD(ca, t0 + 128) }
    K5_CHUNK(cb, ca[0])
  }
  if (threadIdx.x < 4) out[g] = (float)cnt;
}

extern "C" void kernel_launch(void* const* d_in, const int* in_sizes, int n_in,
                              void* d_out, int out_size, void* d_ws, size_t ws_size,
                              hipStream_t stream) {
  const float* kin   = (const float*)d_in[0];
  const float* tda   = (const float*)d_in[1];
  const float* Wsp   = (const float*)d_in[2];
  const float* gamma = (const float*)d_in[3];
  const float* beta  = (const float*)d_in[4];
  const float* Wc    = (const float*)d_in[5];
  const float* lat   = (const float*)d_in[6];
  const float* Wtda  = (const float*)d_in[7];
  const float* btda  = (const float*)d_in[8];

  char* ws = (char*)d_ws;
  float*  xproj    = (float*)(ws + OFF_X);
  float*  partials = (float*)(ws + OFF_PART);
  double* statd    = (double*)(ws + OFF_STAT);
  float*  param    = (float*)(ws + OFF_PARAM);
  unsigned long long* masksB = (unsigned long long*)(ws + OFF_MASK);
  float*  cur2T    = (float*)(ws + OFF_CUR2);
  float*  out      = (float*)d_out;

  k1_gemm  <<<dim3(NBLK_K1), dim3(256), 0, stream>>>(kin, Wsp, xproj, partials);
  k2a_reduce<<<dim3(128),  dim3(256), 0, stream>>>(partials, statd);
  k2b_final<<<dim3(5),     dim3(256), 0, stream>>>(statd, gamma, beta, tda, Wtda, btda, param);
  k3_scan1 <<<dim3(BB),    dim3(64),  0, stream>>>(xproj, param, masksB);
  k4_cur2  <<<dim3(BB),    dim3(256), 0, stream>>>(masksB, Wc, lat, cur2T);
  k5_scan2 <<<dim3(BB),    dim3(64),  0, stream>>>(cur2T, param, out);
}